// Round 11
// baseline (176.846 us; speedup 1.0000x reference)
//
#include <hip/hip_runtime.h>
#include <hip/hip_bf16.h>
#include <cstdint>
#include <cstddef>

using bf16 = __hip_bfloat16;
using short8 = __attribute__((ext_vector_type(8))) short;
using f32x4  = __attribute__((ext_vector_type(4))) float;
using f32x16 = __attribute__((ext_vector_type(16))) float;

#define DEVI __device__ __forceinline__

// async global->LDS, 16B per lane. LDS dest is wave-uniform base + lane*16.
DEVI void async_ld16(const void* g, void* l) {
  __builtin_amdgcn_global_load_lds(
      (const __attribute__((address_space(1))) unsigned int*)g,
      (__attribute__((address_space(3))) unsigned int*)l, 16, 0, 0);
}

DEVI unsigned int cvt_pk_bf16(float lo, float hi) {
  unsigned int r;
  asm("v_cvt_pk_bf16_f32 %0, %1, %2" : "=v"(r) : "v"(lo), "v"(hi));
  return r;
}

// ---------------------------------------------------------------- cvt f32->bf16
__global__ void cvt_f32_bf16(const float* __restrict__ in, bf16* __restrict__ out, int n4) {
  int i = blockIdx.x * blockDim.x + threadIdx.x;
  if (i >= n4) return;
  float4 v = ((const float4*)in)[i];
  union { bf16 h[4]; ushort4 u; } o;
  o.h[0] = __float2bfloat16(v.x);
  o.h[1] = __float2bfloat16(v.y);
  o.h[2] = __float2bfloat16(v.z);
  o.h[3] = __float2bfloat16(v.w);
  ((ushort4*)out)[i] = o.u;
}

// ------------------------------------------- transpose + cvt: in[K][N] -> out[N][K]
__global__ __launch_bounds__(256) void transpose_cvt(
    const float* __restrict__ in, bf16* __restrict__ out, int K, int N) {
  __shared__ float tile[32][33];
  int n0 = blockIdx.x * 32, k0 = blockIdx.y * 32;
  int tx = threadIdx.x & 31, ty = threadIdx.x >> 5;  // 32 x 8
#pragma unroll
  for (int i = 0; i < 32; i += 8)
    tile[ty + i][tx] = in[(size_t)(k0 + ty + i) * N + n0 + tx];
  __syncthreads();
#pragma unroll
  for (int i = 0; i < 32; i += 8)
    out[(size_t)(n0 + ty + i) * K + k0 + tx] = __float2bfloat16(tile[tx][ty + i]);
}

// ------------------- fused wq/wk/wv transpose: wt[4096][1024] = [wq^T | wk^T | wv^T]
__global__ __launch_bounds__(256) void transpose_cvt3(
    const float* __restrict__ wq, const float* __restrict__ wk,
    const float* __restrict__ wv, bf16* __restrict__ wt) {
  __shared__ float tile[32][33];
  int z = blockIdx.z;
  const float* src; int N, coff, roff;
  if (z < 2)       { src = wq; N = 2048; coff = z * 1024; roff = z * 1024; }
  else if (z == 2) { src = wk; N = 1024; coff = 0;        roff = 2048; }
  else             { src = wv; N = 1024; coff = 0;        roff = 3072; }
  int n0 = coff + blockIdx.x * 32, k0 = blockIdx.y * 32;
  int tx = threadIdx.x & 31, ty = threadIdx.x >> 5;
#pragma unroll
  for (int i = 0; i < 32; i += 8)
    tile[ty + i][tx] = src[(size_t)(k0 + ty + i) * N + n0 + tx];
  __syncthreads();
#pragma unroll
  for (int i = 0; i < 32; i += 8)
    wt[(size_t)(roff + blockIdx.x * 32 + ty + i) * 1024 + k0 + tx] =
        __float2bfloat16(tile[tx][ty + i]);
}

// ----------------------- V transpose: Vt[b*8+kvh][hd][t] <- qkv[b*2048+t][3072+kvh*128+hd]
__global__ __launch_bounds__(256) void v_transpose(
    const bf16* __restrict__ qkv, bf16* __restrict__ Vt) {
  __shared__ bf16 tile[32][34];
  int bk = blockIdx.z;                       // 0..15
  int t0 = blockIdx.x * 32, h0 = blockIdx.y * 32;
  int tx = threadIdx.x & 31, ty = threadIdx.x >> 5;  // 32 x 8
  int b = bk >> 3, kvh = bk & 7;
  const bf16* src = qkv + (size_t)(b * 2048) * 4096 + 3072 + kvh * 128;
#pragma unroll
  for (int i = 0; i < 32; i += 8)
    tile[ty + i][tx] = src[(size_t)(t0 + ty + i) * 4096 + h0 + tx];
  __syncthreads();
  bf16* dst = Vt + (size_t)bk * 128 * 2048;
#pragma unroll
  for (int i = 0; i < 32; i += 8)
    dst[(size_t)(h0 + ty + i) * 2048 + t0 + tx] = tile[tx][ty + i];
}

// ---------------------------------------------------------------- rope table
__global__ void rope_tab(float2* __restrict__ tab) {
  int t = blockIdx.x, i = threadIdx.x;  // T blocks x 64 threads
  float ex = -2.f * (float)i * (1.f / 128.f);
  float theta = exp2f(ex * 19.9315685693241741f);  // log2(1e6)
  float f = (float)t * theta;
  float sv, cv;
  sincosf(f, &sv, &cv);
  tab[t * 64 + i] = make_float2(cv, sv);
}

// ------- 128x128 GEMM, SINGLE-buffered LDS (32KB) -> 4 blocks/CU TLP. bf16 out.
__global__ __launch_bounds__(256, 4) void gemm_bt4(
    const bf16* __restrict__ A, const bf16* __restrict__ Bt,
    bf16* __restrict__ C, int M, int N, int K) {
  __shared__ alignas(16) bf16 As[128 * 64];
  __shared__ alignas(16) bf16 Bs[128 * 64];
  const int tid = threadIdx.x, lane = tid & 63, w = tid >> 6;
  const int wm = w >> 1, wn = w & 1;
  const int m0 = blockIdx.y * 128, n0 = blockIdx.x * 128;
  const int nt = K >> 6;
  f32x4 acc[4][4] = {};

  const int srow = lane >> 3;
  const int scb  = (lane & 7) * 16;

  for (int kt = 0; kt < nt; ++kt) {
#pragma unroll
    for (int i = 0; i < 4; i++) {
      int row = w * 32 + i * 8 + srow;
      int src_cb = scb ^ ((row & 7) << 4);
      async_ld16((const char*)(A  + (size_t)(m0 + row) * K + kt * 64) + src_cb,
                 (char*)As + w * 4096 + i * 1024);
      async_ld16((const char*)(Bt + (size_t)(n0 + row) * K + kt * 64) + src_cb,
                 (char*)Bs + w * 4096 + i * 1024);
    }
    asm volatile("s_waitcnt vmcnt(0)" ::: "memory");
    __builtin_amdgcn_s_barrier();               // tile landed for all waves
#pragma unroll
    for (int ks = 0; ks < 2; ks++) {
      short8 af[4], bfr[4];
#pragma unroll
      for (int mi = 0; mi < 4; mi++) {
        int row = wm * 64 + mi * 16 + (lane & 15);
        int cb = (ks * 64 + (lane >> 4) * 16) ^ ((row & 7) << 4);
        af[mi] = *(const short8*)((const char*)As + row * 128 + cb);
      }
#pragma unroll
      for (int ni = 0; ni < 4; ni++) {
        int row = wn * 64 + ni * 16 + (lane & 15);
        int cb = (ks * 64 + (lane >> 4) * 16) ^ ((row & 7) << 4);
        bfr[ni] = *(const short8*)((const char*)Bs + row * 128 + cb);
      }
#pragma unroll
      for (int mi = 0; mi < 4; mi++)
#pragma unroll
        for (int ni = 0; ni < 4; ni++)
          acc[mi][ni] = __builtin_amdgcn_mfma_f32_16x16x32_bf16(af[mi], bfr[ni], acc[mi][ni], 0, 0, 0);
    }
    __builtin_amdgcn_s_barrier();               // all done reading; safe to overwrite
    __builtin_amdgcn_sched_barrier(0);
  }

  const int c0 = n0 + wn * 64 + (lane & 15);
  const int r0 = m0 + wm * 64 + (lane >> 4) * 4;
#pragma unroll
  for (int mi = 0; mi < 4; mi++)
#pragma unroll
    for (int ni = 0; ni < 4; ni++)
#pragma unroll
      for (int r = 0; r < 4; r++) {
        size_t idx = (size_t)(r0 + mi * 16 + r) * N + (c0 + ni * 16);
        C[idx] = __float2bfloat16(acc[mi][ni][r]);
      }
}

// ------- 128x128 GEMM, 2-deep counted vmcnt(8) (for out-proj: only 256 blocks), f32 out
__global__ __launch_bounds__(256, 2) void gemm_out(
    const bf16* __restrict__ A, const bf16* __restrict__ Bt,
    float* __restrict__ C, int M, int N, int K) {
  __shared__ alignas(16) bf16 As[2][128 * 64];
  __shared__ alignas(16) bf16 Bs[2][128 * 64];
  const int tid = threadIdx.x, lane = tid & 63, w = tid >> 6;
  const int wm = w >> 1, wn = w & 1;
  const int m0 = blockIdx.y * 128, n0 = blockIdx.x * 128;
  const int nt = K >> 6;
  f32x4 acc[4][4] = {};

  const int srow = lane >> 3;
  const int scb  = (lane & 7) * 16;

  auto stage = [&](int buf, int kt) {
#pragma unroll
    for (int i = 0; i < 4; i++) {
      int row = w * 32 + i * 8 + srow;
      int src_cb = scb ^ ((row & 7) << 4);
      async_ld16((const char*)(A  + (size_t)(m0 + row) * K + kt * 64) + src_cb,
                 (char*)As[buf] + w * 4096 + i * 1024);
      async_ld16((const char*)(Bt + (size_t)(n0 + row) * K + kt * 64) + src_cb,
                 (char*)Bs[buf] + w * 4096 + i * 1024);
    }
  };

  stage(0, 0);
  stage(1, 1);

  for (int kt = 0; kt < nt; ++kt) {
    const int buf = kt & 1;
    if (kt + 1 < nt) asm volatile("s_waitcnt vmcnt(8)" ::: "memory");
    else             asm volatile("s_waitcnt vmcnt(0)" ::: "memory");
    __builtin_amdgcn_s_barrier();
#pragma unroll
    for (int ks = 0; ks < 2; ks++) {
      short8 af[4], bfr[4];
#pragma unroll
      for (int mi = 0; mi < 4; mi++) {
        int row = wm * 64 + mi * 16 + (lane & 15);
        int cb = (ks * 64 + (lane >> 4) * 16) ^ ((row & 7) << 4);
        af[mi] = *(const short8*)((const char*)As[buf] + row * 128 + cb);
      }
#pragma unroll
      for (int ni = 0; ni < 4; ni++) {
        int row = wn * 64 + ni * 16 + (lane & 15);
        int cb = (ks * 64 + (lane >> 4) * 16) ^ ((row & 7) << 4);
        bfr[ni] = *(const short8*)((const char*)Bs[buf] + row * 128 + cb);
      }
#pragma unroll
      for (int mi = 0; mi < 4; mi++)
#pragma unroll
        for (int ni = 0; ni < 4; ni++)
          acc[mi][ni] = __builtin_amdgcn_mfma_f32_16x16x32_bf16(af[mi], bfr[ni], acc[mi][ni], 0, 0, 0);
    }
    __builtin_amdgcn_s_barrier();
    __builtin_amdgcn_sched_barrier(0);
    if (kt + 2 < nt) stage(buf, kt + 2);
  }

  const int c0 = n0 + wn * 64 + (lane & 15);
  const int r0 = m0 + wm * 64 + (lane >> 4) * 4;
#pragma unroll
  for (int mi = 0; mi < 4; mi++)
#pragma unroll
    for (int ni = 0; ni < 4; ni++)
#pragma unroll
      for (int r = 0; r < 4; r++)
        C[(size_t)(r0 + mi * 16 + r) * N + (c0 + ni * 16)] = acc[mi][ni][r];
}

// ---------- RMSNorm + RoPE + relayout, vectorized 16B/lane. Q pre-scaled by
// (1/sqrt(128))*log2(e) so flash's QK^T lands directly in the log2 softmax domain.
__global__ __launch_bounds__(256) void norm_rope(
    const bf16* __restrict__ qkv, const float* __restrict__ qw, const float* __restrict__ kw,
    const float2* __restrict__ tab,
    bf16* __restrict__ Qh, bf16* __restrict__ Kh) {
  const int w = threadIdx.x >> 6, lane = threadIdx.x & 63;
  const int grp = lane >> 4, l = lane & 15;
  const int flat = blockIdx.x * 16 + w * 4 + grp;
  const int m = flat / 24, slot = flat - m * 24;
  const int b = m >> 11, t = m & 2047;

  const int type = slot >= 16;
  const int h = type ? slot - 16 : slot;
  const int col = type ? 2048 + h * 128 : h * 128;

  union { short8 s; bf16 h[8]; } u;
  u.s = *(const short8*)(qkv + (size_t)m * 4096 + col + l * 8);
  float x[8];
#pragma unroll
  for (int j = 0; j < 8; j++) x[j] = __bfloat162float(u.h[j]);

  float ss = 0.f;
#pragma unroll
  for (int j = 0; j < 8; j++) ss += x[j] * x[j];
#pragma unroll
  for (int o = 1; o < 16; o <<= 1) ss += __shfl_xor(ss, o);
  float rms = sqrtf(ss * (1.f / 128.f));
  float inv = 1.f / (rms + 1e-6f);
  if (!type) inv *= 0.12751744416163417f;  // fold softmax scale*log2(e) into Q

  const float* wn = type ? kw : qw;
  float4 w0 = *(const float4*)(wn + l * 8);
  float4 w1 = *(const float4*)(wn + l * 8 + 4);
  float wv[8] = {w0.x, w0.y, w0.z, w0.w, w1.x, w1.y, w1.z, w1.w};

  const float4* tb = (const float4*)(tab + t * 64 + l * 4);
  float4 t0 = tb[0], t1 = tb[1];
  float cs[8] = {t0.x, t0.y, t0.z, t0.w, t1.x, t1.y, t1.z, t1.w};

  union { short8 s; bf16 h[8]; } o;
#pragma unroll
  for (int i = 0; i < 4; i++) {
    float re = wv[2 * i] * x[2 * i] * inv;
    float im = wv[2 * i + 1] * x[2 * i + 1] * inv;
    float c = cs[2 * i], s = cs[2 * i + 1];
    o.h[2 * i]     = __float2bfloat16(re * c - im * s);
    o.h[2 * i + 1] = __float2bfloat16(re * s + im * c);
  }
  bf16* dst = type
      ? Kh + ((size_t)(b * 8 + h) * 2048 + t) * 128 + l * 8
      : Qh + ((size_t)(b * 16 + h) * 2048 + t) * 128 + l * 8;
  *(short8*)dst = o.s;
}

// -------- flash attention v10: in-block kv-split, Q pre-scaled (unchanged from R9)
__global__ __launch_bounds__(512, 1) void flash_attn10(
    const bf16* __restrict__ Qh, const bf16* __restrict__ Kh,
    const bf16* __restrict__ Vt, bf16* __restrict__ Y) {
  __shared__ alignas(16) bf16 KB[4][64 * 128];   // [buf=set*2+grp][key][hd] 256B rows swz
  __shared__ alignas(16) bf16 VB[4][128 * 64];   // [buf][hd][key] 128B rows swz
  __shared__ float MLs[128][2];
  const int tid = threadIdx.x, lane = tid & 63, w = tid >> 6;
  const int hi = lane >> 5, lq = lane & 31;
  const int grp = w >> 2, wl = w & 3;

  const int g = blockIdx.x;
  const int bh = (g & 7) * 4 + ((g >> 3) & 3);   // XCD-grouped bh
  const int p  = g >> 5;                         // 0..7
  const int b = bh >> 4, h = bh & 15, kvh = h >> 1;

  const bf16* Qg = Qh + (size_t)(b * 16 + h) * 2048 * 128;
  const bf16* Kg = Kh + (size_t)(b * 8 + kvh) * 2048 * 128;
  const bf16* Vg = Vt + (size_t)(b * 8 + kvh) * 128 * 2048;

  short8 qf[8];
  f32x16 oacc[4];
  float m, l;
  int qw = 0, qg = 0;

  auto stage2 = [&](int set, int k0e) {
#pragma unroll
    for (int gb = 0; gb < 2; gb++) {
      const int k0 = k0e + gb * 64;
      char* kb = (char*)KB[set * 2 + gb];
      char* vb = (char*)VB[set * 2 + gb];
#pragma unroll
      for (int i = 0; i < 2; i++) {
        int c = w * 2 + i;
        {
          int row = c * 4 + (lane >> 4);
          int cb = ((lane & 15) * 16) ^ ((row & 7) << 4);
          async_ld16((const char*)Kg + (size_t)(k0 + row) * 256 + cb, kb + c * 1024);
        }
        {
          int row = c * 8 + (lane >> 3);
          int cb = ((lane & 7) * 16) ^ ((row & 7) << 4);
          async_ld16((const char*)Vg + (size_t)row * 4096 + (size_t)k0 * 2 + cb, vb + c * 1024);
        }
      }
    }
  };

  auto setupTile = [&](int q0) {
    qw = q0 + wl * 32;
    qg = qw + lq;
#pragma unroll
    for (int dc = 0; dc < 8; dc++)
      qf[dc] = *(const short8*)(Qg + (size_t)qg * 128 + dc * 16 + hi * 8);
#pragma unroll
    for (int dc = 0; dc < 4; dc++)
#pragma unroll
      for (int r = 0; r < 16; r++) oacc[dc][r] = 0.f;
    m = -1e30f;
    l = 0.f;
  };

  auto computeStep = [&](int bufI, int k0) {
    f32x16 st[2] = {};
#pragma unroll
    for (int kc = 0; kc < 2; kc++) {
      int row = kc * 32 + lq;
      int swz = (row & 7) << 4;
      const char* kbase = (const char*)KB[bufI] + row * 256;
#pragma unroll
      for (int dc = 0; dc < 8; dc++) {
        short8 kf = *(const short8*)(kbase + ((dc * 32 + hi * 16) ^ swz));
        st[kc] = __builtin_amdgcn_mfma_f32_32x32x16_bf16(kf, qf[dc], st[kc], 0, 0, 0);
      }
    }
    const bool msk = (k0 + 63 > qw);
    if (msk) {
#pragma unroll
      for (int kc = 0; kc < 2; kc++)
#pragma unroll
        for (int rr = 0; rr < 16; rr++) {
          int kg = k0 + kc * 32 + (rr & 3) + 8 * (rr >> 2) + 4 * hi;
          if (kg > qg) st[kc][rr] = -1e30f;
        }
    }
    float mx[16];
#pragma unroll
    for (int rr = 0; rr < 16; rr++) mx[rr] = fmaxf(st[0][rr], st[1][rr]);
#pragma unroll
    for (int off = 8; off >= 1; off >>= 1)
#pragma unroll
      for (int rr = 0; rr < 8; rr++)
        if (rr < off) mx[rr] = fmaxf(mx[rr], mx[rr + off]);
    float pm = fmaxf(mx[0], __shfl_xor(mx[0], 32));
    if (__any(pm > m + 8.f)) {
      float mnew = fmaxf(m, pm);
      float alpha = exp2f(m - mnew);
      m = mnew;
      l *= alpha;
      float al[16];
#pragma unroll
      for (int rr = 0; rr < 16; rr++)
        al[rr] = __shfl(alpha, (rr & 3) + 8 * (rr >> 2) + 4 * hi);
#pragma unroll
      for (int dc = 0; dc < 4; dc++)
#pragma unroll
        for (int rr = 0; rr < 16; rr++) oacc[dc][rr] *= al[rr];
    }
#pragma unroll
    for (int kc = 0; kc < 2; kc++)
#pragma unroll
      for (int rr = 0; rr < 16; rr++) st[kc][rr] = exp2f(st[kc][rr] - m);
    float sm[16];
#pragma unroll
    for (int rr = 0; rr < 16; rr++) sm[rr] = st[0][rr] + st[1][rr];
#pragma unroll
    for (int off = 8; off >= 1; off >>= 1)
#pragma unroll
      for (int rr = 0; rr < 8; rr++)
        if (rr < off) sm[rr] += sm[rr + off];
    l += sm[0] + __shfl_xor(sm[0], 32);
    short8 af[4];
#pragma unroll
    for (int kc = 0; kc < 2; kc++)
#pragma unroll
      for (int sb = 0; sb < 2; sb++) {
        int base = sb * 8;
        unsigned int a01 = cvt_pk_bf16(st[kc][base + 0], st[kc][base + 1]);
        unsigned int a23 = cvt_pk_bf16(st[kc][base + 2], st[kc][base + 3]);
        unsigned int b01 = cvt_pk_bf16(st[kc][base + 4], st[kc][base + 5]);
        unsigned int b23 = cvt_pk_bf16(st[kc][base + 6], st[kc][base + 7]);
        unsigned int xa01 = (unsigned int)__shfl_xor((int)a01, 32);
        unsigned int xa23 = (unsigned int)__shfl_xor((int)a23, 32);
        unsigned int xb01 = (unsigned int)__shfl_xor((int)b01, 32);
        unsigned int xb23 = (unsigned int)__shfl_xor((int)b23, 32);
        union { unsigned int u[4]; short8 s; } f;
        f.u[0] = hi ? xb01 : a01;
        f.u[1] = hi ? xb23 : a23;
        f.u[2] = hi ? b01 : xa01;
        f.u[3] = hi ? b23 : xa23;
        af[kc * 2 + sb] = f.s;
      }
#pragma unroll
    for (int dc = 0; dc < 4; dc++) {
      int row = dc * 32 + lq;
      int swz = (row & 7) << 4;
      const char* vbase = (const char*)VB[bufI] + row * 128;
#pragma unroll
      for (int ks = 0; ks < 4; ks++) {
        short8 vf = *(const short8*)(vbase + ((ks * 32 + hi * 16) ^ swz));
        oacc[dc] = __builtin_amdgcn_mfma_f32_32x32x16_bf16(af[ks], vf, oacc[dc], 0, 0, 0);
      }
    }
  };

  auto runRounds = [&](int n) {
    const int R = n >> 1;
    for (int r = 0; r < R; ++r) {
      asm volatile("s_waitcnt vmcnt(0)" ::: "memory");
      __builtin_amdgcn_s_barrier();
      if (r + 1 < R) stage2((r + 1) & 1, (2 * r + 2) * 64);
      __builtin_amdgcn_sched_barrier(0);
      const int s = 2 * r + grp, k0 = s * 64;
      const int bufI = (r & 1) * 2 + grp;
      if (k0 < qw + 32) computeStep(bufI, k0);
    }
  };

  auto writePartials = [&]() {
    float* base = (wl < 2) ? (float*)KB[2] : (float*)VB[2];
#pragma unroll
    for (int dc = 0; dc < 4; dc++)
#pragma unroll
      for (int rr = 0; rr < 16; rr++) {
        int q = (wl & 1) * 32 + (rr & 3) + 8 * (rr >> 2) + 4 * hi;
        base[q * 128 + dc * 32 + lq] = oacc[dc][rr];
      }
    if (lane < 32) {
      MLs[wl * 32 + lane][0] = m;
      MLs[wl * 32 + lane][1] = l;
    }
  };

  auto mergeAndY = [&](int q0) {
    float m1 = MLs[wl * 32 + lq][0], l1 = MLs[wl * 32 + lq][1];
    float mN = fmaxf(m, m1);
    float e0 = exp2f(m - mN), e1 = exp2f(m1 - mN);
    float lT = l * e0 + l1 * e1;
    float inv = 1.f / lT;
    float e0r[16], e1r[16], ivr[16];
#pragma unroll
    for (int rr = 0; rr < 16; rr++) {
      int src = (rr & 3) + 8 * (rr >> 2) + 4 * hi;
      e0r[rr] = __shfl(e0, src);
      e1r[rr] = __shfl(e1, src);
      ivr[rr] = __shfl(inv, src);
    }
    const float* base = (wl < 2) ? (const float*)KB[2] : (const float*)VB[2];
#pragma unroll
    for (int dc = 0; dc < 4; dc++)
#pragma unroll
      for (int rr = 0; rr < 16; rr++) {
        int q = (wl & 1) * 32 + (rr & 3) + 8 * (rr >> 2) + 4 * hi;
        float o1 = base[q * 128 + dc * 32 + lq];
        float oT = oacc[dc][rr] * e0r[rr] + o1 * e1r[rr];
        int t = q0 + wl * 32 + (rr & 3) + 8 * (rr >> 2) + 4 * hi;
        Y[(size_t)(b * 2048 + t) * 2048 + h * 128 + dc * 32 + lq] =
            __float2bfloat16(oT * ivr[rr]);
      }
  };

  const int jA = 15 - p, jB = p;
  const int q0A = jA * 128, nA = 2 * jA + 2;
  const int q0B = jB * 128, nB = 2 * jB + 2;

  setupTile(q0A);
  stage2(0, 0);
  runRounds(nA);
  __syncthreads();
  stage2(0, 0);
  if (grp == 1) writePartials();
  __syncthreads();
  if (grp == 0) mergeAndY(q0A);
  setupTile(q0B);
  runRounds(nB);
  __syncthreads();
  if (grp == 1) writePartials();
  __syncthreads();
  if (grp == 0) mergeAndY(q0B);
}

// ---------------------------------------------------------------- launcher
extern "C" void kernel_launch(void* const* d_in, const int* in_sizes, int n_in,
                              void* d_out, int out_size, void* d_ws, size_t ws_size,
                              hipStream_t stream) {
  (void)in_sizes; (void)n_in; (void)out_size; (void)ws_size;
  const float* x   = (const float*)d_in[0];
  const float* wq  = (const float*)d_in[1];
  const float* wk  = (const float*)d_in[2];
  const float* wv  = (const float*)d_in[3];
  const float* wo  = (const float*)d_in[4];
  const float* qnw = (const float*)d_in[5];
  const float* knw = (const float*)d_in[6];
  float* out = (float*)d_out;
  char* ws = (char*)d_ws;
  const size_t MB = 1u << 20;
  bf16*   xb  = (bf16*)(ws + 0 * MB);    // [4096][1024]
  bf16*   wt  = (bf16*)(ws + 8 * MB);    // [4096][1024]  rows: wq^T | wk^T | wv^T
  bf16*   wot = (bf16*)(ws + 16 * MB);   // [1024][2048]
  bf16*   qkv = (bf16*)(ws + 20 * MB);   // [4096][4096]
  float2* tab = (float2*)(ws + 52 * MB); // [2048][64]
  bf16*   Qh  = (bf16*)(ws + 53 * MB);   // [2][16][2048][128] (pre-scaled)
  bf16*   Kh  = (bf16*)(ws + 69 * MB);   // [2][8][2048][128]
  bf16*   Vtr = (bf16*)(ws + 77 * MB);   // [2][8][128][2048]  (V transposed)
  bf16*   Yb  = (bf16*)(ws + 85 * MB);   // [4096][2048]

  cvt_f32_bf16<<<4096, 256, 0, stream>>>(x, xb, 1048576);
  transpose_cvt3<<<dim3(32, 32, 4), 256, 0, stream>>>(wq, wk, wv, wt);
  transpose_cvt<<<dim3(32, 64), 256, 0, stream>>>(wo, wot, 2048, 1024);
  rope_tab<<<2048, 64, 0, stream>>>(tab);
  gemm_bt4<<<dim3(32, 32), 256, 0, stream>>>(xb, wt, qkv, 4096, 4096, 1024);
  norm_rope<<<6144, 256, 0, stream>>>(qkv, qnw, knw, tab, Qh, Kh);
  v_transpose<<<dim3(64, 4, 16), 256, 0, stream>>>(qkv, Vtr);
  flash_attn10<<<256, 512, 0, stream>>>(Qh, Kh, Vtr, Yb);
  gemm_out<<<dim3(8, 32), 256, 0, stream>>>(Yb, wot, out, 4096, 1024, 2048);
}

// Round 13
// 166.599 us; speedup vs baseline: 1.0615x; 1.0615x over previous
//
#include <hip/hip_runtime.h>
#include <hip/hip_bf16.h>
#include <cstdint>
#include <cstddef>

using bf16 = __hip_bfloat16;
using short8 = __attribute__((ext_vector_type(8))) short;
using f32x4  = __attribute__((ext_vector_type(4))) float;
using f32x16 = __attribute__((ext_vector_type(16))) float;

#define DEVI __device__ __forceinline__

// async global->LDS, 16B per lane. LDS dest is wave-uniform base + lane*16.
DEVI void async_ld16(const void* g, void* l) {
  __builtin_amdgcn_global_load_lds(
      (const __attribute__((address_space(1))) unsigned int*)g,
      (__attribute__((address_space(3))) unsigned int*)l, 16, 0, 0);
}

DEVI unsigned int cvt_pk_bf16(float lo, float hi) {
  unsigned int r;
  asm("v_cvt_pk_bf16_f32 %0, %1, %2" : "=v"(r) : "v"(lo), "v"(hi));
  return r;
}

// ---------------------------------------------------------------- cvt f32->bf16
__global__ void cvt_f32_bf16(const float* __restrict__ in, bf16* __restrict__ out, int n4) {
  int i = blockIdx.x * blockDim.x + threadIdx.x;
  if (i >= n4) return;
  float4 v = ((const float4*)in)[i];
  union { bf16 h[4]; ushort4 u; } o;
  o.h[0] = __float2bfloat16(v.x);
  o.h[1] = __float2bfloat16(v.y);
  o.h[2] = __float2bfloat16(v.z);
  o.h[3] = __float2bfloat16(v.w);
  ((ushort4*)out)[i] = o.u;
}

// ------------------------------------------- transpose + cvt: in[K][N] -> out[N][K]
__global__ __launch_bounds__(256) void transpose_cvt(
    const float* __restrict__ in, bf16* __restrict__ out, int K, int N) {
  __shared__ float tile[32][33];
  int n0 = blockIdx.x * 32, k0 = blockIdx.y * 32;
  int tx = threadIdx.x & 31, ty = threadIdx.x >> 5;  // 32 x 8
#pragma unroll
  for (int i = 0; i < 32; i += 8)
    tile[ty + i][tx] = in[(size_t)(k0 + ty + i) * N + n0 + tx];
  __syncthreads();
#pragma unroll
  for (int i = 0; i < 32; i += 8)
    out[(size_t)(n0 + ty + i) * K + k0 + tx] = __float2bfloat16(tile[tx][ty + i]);
}

// ------------------- fused wq/wk/wv transpose: wt[4096][1024] = [wq^T | wk^T | wv^T]
__global__ __launch_bounds__(256) void transpose_cvt3(
    const float* __restrict__ wq, const float* __restrict__ wk,
    const float* __restrict__ wv, bf16* __restrict__ wt) {
  __shared__ float tile[32][33];
  int z = blockIdx.z;
  const float* src; int N, coff, roff;
  if (z < 2)       { src = wq; N = 2048; coff = z * 1024; roff = z * 1024; }
  else if (z == 2) { src = wk; N = 1024; coff = 0;        roff = 2048; }
  else             { src = wv; N = 1024; coff = 0;        roff = 3072; }
  int n0 = coff + blockIdx.x * 32, k0 = blockIdx.y * 32;
  int tx = threadIdx.x & 31, ty = threadIdx.x >> 5;
#pragma unroll
  for (int i = 0; i < 32; i += 8)
    tile[ty + i][tx] = src[(size_t)(k0 + ty + i) * N + n0 + tx];
  __syncthreads();
#pragma unroll
  for (int i = 0; i < 32; i += 8)
    wt[(size_t)(roff + blockIdx.x * 32 + ty + i) * 1024 + k0 + tx] =
        __float2bfloat16(tile[tx][ty + i]);
}

// ---------------------------------------------------------------- rope table
__global__ void rope_tab(float2* __restrict__ tab) {
  int t = blockIdx.x, i = threadIdx.x;  // T blocks x 64 threads
  float ex = -2.f * (float)i * (1.f / 128.f);
  float theta = exp2f(ex * 19.9315685693241741f);  // log2(1e6)
  float f = (float)t * theta;
  float sv, cv;
  sincosf(f, &sv, &cv);
  tab[t * 64 + i] = make_float2(cv, sv);
}

// ------- fused QKV GEMM (128x128, 2-deep counted vmcnt(8), 2 blocks/CU) with
// per-head epilogue: bx<16 Q-head (RMSNorm+RoPE+scale -> Qh), 16..23 K-head
// (RMSNorm+RoPE -> Kh), 24..31 V-head (LDS transpose -> Vt[d][t]).
__global__ __launch_bounds__(256, 2) void gemm_qkv(
    const bf16* __restrict__ A, const bf16* __restrict__ Bt,
    const float* __restrict__ qnw, const float* __restrict__ knw,
    const float2* __restrict__ tab,
    bf16* __restrict__ Qh, bf16* __restrict__ Kh, bf16* __restrict__ Vt) {
  __shared__ alignas(16) bf16 As[2][128 * 64];
  __shared__ alignas(16) bf16 Bs[2][128 * 64];
  const int tid = threadIdx.x, lane = tid & 63, w = tid >> 6;
  const int wm = w >> 1, wn = w & 1;
  const int bx = blockIdx.x;
  const int m0 = blockIdx.y * 128, n0 = bx * 128;
  const int K = 1024, nt = 16;
  f32x4 acc[4][4] = {};

  const int srow = lane >> 3;
  const int scb  = (lane & 7) * 16;

  auto stage = [&](int buf, int kt) {
#pragma unroll
    for (int i = 0; i < 4; i++) {
      int row = w * 32 + i * 8 + srow;
      int src_cb = scb ^ ((row & 7) << 4);
      async_ld16((const char*)(A  + (size_t)(m0 + row) * K + kt * 64) + src_cb,
                 (char*)As[buf] + w * 4096 + i * 1024);
      async_ld16((const char*)(Bt + (size_t)(n0 + row) * K + kt * 64) + src_cb,
                 (char*)Bs[buf] + w * 4096 + i * 1024);
    }
  };

  stage(0, 0);
  stage(1, 1);

  for (int kt = 0; kt < nt; ++kt) {
    const int buf = kt & 1;
    if (kt + 1 < nt) asm volatile("s_waitcnt vmcnt(8)" ::: "memory");
    else             asm volatile("s_waitcnt vmcnt(0)" ::: "memory");
    __builtin_amdgcn_s_barrier();
#pragma unroll
    for (int ks = 0; ks < 2; ks++) {
      short8 af[4], bfr[4];
#pragma unroll
      for (int mi = 0; mi < 4; mi++) {
        int row = wm * 64 + mi * 16 + (lane & 15);
        int cb = (ks * 64 + (lane >> 4) * 16) ^ ((row & 7) << 4);
        af[mi] = *(const short8*)((const char*)As[buf] + row * 128 + cb);
      }
#pragma unroll
      for (int ni = 0; ni < 4; ni++) {
        int row = wn * 64 + ni * 16 + (lane & 15);
        int cb = (ks * 64 + (lane >> 4) * 16) ^ ((row & 7) << 4);
        bfr[ni] = *(const short8*)((const char*)Bs[buf] + row * 128 + cb);
      }
#pragma unroll
      for (int mi = 0; mi < 4; mi++)
#pragma unroll
        for (int ni = 0; ni < 4; ni++)
          acc[mi][ni] = __builtin_amdgcn_mfma_f32_16x16x32_bf16(af[mi], bfr[ni], acc[mi][ni], 0, 0, 0);
    }
    __builtin_amdgcn_s_barrier();
    __builtin_amdgcn_sched_barrier(0);
    if (kt + 2 < nt) stage(buf, kt + 2);
  }

  const int b = m0 >> 11;  // uniform per block (128 | 2048)

  if (bx < 24) {
    // ---------- Q/K epilogue: RMSNorm + RoPE, write head-major layout
    __syncthreads();                     // all LDS traffic of main loop done
    float* ssb = (float*)As;             // [2 (wn)][128 rows] partial sum-sq
    float s[4][4];
#pragma unroll
    for (int mi = 0; mi < 4; mi++)
#pragma unroll
      for (int r = 0; r < 4; r++) {
        float v0 = acc[mi][0][r], v1 = acc[mi][1][r];
        float v2 = acc[mi][2][r], v3 = acc[mi][3][r];
        float t = v0 * v0 + v1 * v1 + v2 * v2 + v3 * v3;
        t += __shfl_xor(t, 1);
        t += __shfl_xor(t, 2);
        t += __shfl_xor(t, 4);
        t += __shfl_xor(t, 8);
        s[mi][r] = t;
      }
    if ((lane & 15) == 0) {
#pragma unroll
      for (int mi = 0; mi < 4; mi++)
#pragma unroll
        for (int r = 0; r < 4; r++)
          ssb[wn * 128 + wm * 64 + mi * 16 + (lane >> 4) * 4 + r] = s[mi][r];
    }
    __syncthreads();

    const int isQ = (bx < 16);
    const int h = isQ ? bx : bx - 16;
    const float* wnp = isQ ? qnw : knw;
    bf16* dst = isQ ? Qh : Kh;
    const int NHH = isQ ? 16 : 8;
    const float qs = isQ ? 0.12751744416163417f : 1.f;  // fold softmax*log2e into Q
    float wd[4];
#pragma unroll
    for (int ni = 0; ni < 4; ni++) wd[ni] = wnp[wn * 64 + ni * 16 + (lane & 15)];

#pragma unroll
    for (int mi = 0; mi < 4; mi++)
#pragma unroll
      for (int r = 0; r < 4; r++) {
        int rl = wm * 64 + mi * 16 + (lane >> 4) * 4 + r;
        float tot = ssb[rl] + ssb[128 + rl];
        float inv = qs / (sqrtf(tot * 0.0078125f) + 1e-6f);
        int t = (m0 + rl) & 2047;
        bf16* drow = dst + ((size_t)(b * NHH + h) * 2048 + t) * 128;
#pragma unroll
        for (int ni = 0; ni < 4; ni++) {
          int d = wn * 64 + ni * 16 + (lane & 15);
          float val = acc[mi][ni][r] * inv * wd[ni];
          float prt = __shfl_xor(val, 1);
          float2 cs = tab[t * 64 + (d >> 1)];
          float o = (d & 1) ? (prt * cs.y + val * cs.x)
                            : (val * cs.x - prt * cs.y);
          drow[d] = __float2bfloat16(o);
        }
      }
  } else {
    // ---------- V epilogue: transpose 128x128 tile via LDS -> Vt[b*8+vh][d][t]
    __syncthreads();
    bf16* vt = (bf16*)As;                // [128 d][128 t] rows 256B, XOR-swizzled
    const int vh = bx - 24;
#pragma unroll
    for (int mi = 0; mi < 4; mi++)
#pragma unroll
      for (int ni = 0; ni < 4; ni++) {
        int d = wn * 64 + ni * 16 + (lane & 15);
        int tl = wm * 64 + mi * 16 + (lane >> 4) * 4;
        unsigned int p0 = cvt_pk_bf16(acc[mi][ni][0], acc[mi][ni][1]);
        unsigned int p1 = cvt_pk_bf16(acc[mi][ni][2], acc[mi][ni][3]);
        int byte = d * 256 + ((tl * 2) ^ ((d & 7) << 4));
        *(uint2*)((char*)vt + byte) = make_uint2(p0, p1);
      }
    __syncthreads();
    bf16* dstV = Vt + (size_t)(b * 8 + vh) * 128 * 2048 + (m0 & 2047);
#pragma unroll
    for (int i = 0; i < 8; i++) {
      int flat = tid + i * 256;          // 2048 granules: d = flat>>4, g = flat&15
      int d = flat >> 4, g = flat & 15;
      short8 v = *(const short8*)((const char*)vt + d * 256 + ((g * 16) ^ ((d & 7) << 4)));
      *(short8*)(dstV + (size_t)d * 2048 + g * 8) = v;
    }
  }
}

// ------- 128x128 out-proj GEMM, 2-deep counted vmcnt(8), f32 out
__global__ __launch_bounds__(256, 2) void gemm_out(
    const bf16* __restrict__ A, const bf16* __restrict__ Bt,
    float* __restrict__ C, int M, int N, int K) {
  __shared__ alignas(16) bf16 As[2][128 * 64];
  __shared__ alignas(16) bf16 Bs[2][128 * 64];
  const int tid = threadIdx.x, lane = tid & 63, w = tid >> 6;
  const int wm = w >> 1, wn = w & 1;
  const int m0 = blockIdx.y * 128, n0 = blockIdx.x * 128;
  const int nt = K >> 6;
  f32x4 acc[4][4] = {};

  const int srow = lane >> 3;
  const int scb  = (lane & 7) * 16;

  auto stage = [&](int buf, int kt) {
#pragma unroll
    for (int i = 0; i < 4; i++) {
      int row = w * 32 + i * 8 + srow;
      int src_cb = scb ^ ((row & 7) << 4);
      async_ld16((const char*)(A  + (size_t)(m0 + row) * K + kt * 64) + src_cb,
                 (char*)As[buf] + w * 4096 + i * 1024);
      async_ld16((const char*)(Bt + (size_t)(n0 + row) * K + kt * 64) + src_cb,
                 (char*)Bs[buf] + w * 4096 + i * 1024);
    }
  };

  stage(0, 0);
  stage(1, 1);

  for (int kt = 0; kt < nt; ++kt) {
    const int buf = kt & 1;
    if (kt + 1 < nt) asm volatile("s_waitcnt vmcnt(8)" ::: "memory");
    else             asm volatile("s_waitcnt vmcnt(0)" ::: "memory");
    __builtin_amdgcn_s_barrier();
#pragma unroll
    for (int ks = 0; ks < 2; ks++) {
      short8 af[4], bfr[4];
#pragma unroll
      for (int mi = 0; mi < 4; mi++) {
        int row = wm * 64 + mi * 16 + (lane & 15);
        int cb = (ks * 64 + (lane >> 4) * 16) ^ ((row & 7) << 4);
        af[mi] = *(const short8*)((const char*)As[buf] + row * 128 + cb);
      }
#pragma unroll
      for (int ni = 0; ni < 4; ni++) {
        int row = wn * 64 + ni * 16 + (lane & 15);
        int cb = (ks * 64 + (lane >> 4) * 16) ^ ((row & 7) << 4);
        bfr[ni] = *(const short8*)((const char*)Bs[buf] + row * 128 + cb);
      }
#pragma unroll
      for (int mi = 0; mi < 4; mi++)
#pragma unroll
        for (int ni = 0; ni < 4; ni++)
          acc[mi][ni] = __builtin_amdgcn_mfma_f32_16x16x32_bf16(af[mi], bfr[ni], acc[mi][ni], 0, 0, 0);
    }
    __builtin_amdgcn_s_barrier();
    __builtin_amdgcn_sched_barrier(0);
    if (kt + 2 < nt) stage(buf, kt + 2);
  }

  const int c0 = n0 + wn * 64 + (lane & 15);
  const int r0 = m0 + wm * 64 + (lane >> 4) * 4;
#pragma unroll
  for (int mi = 0; mi < 4; mi++)
#pragma unroll
    for (int ni = 0; ni < 4; ni++)
#pragma unroll
      for (int r = 0; r < 4; r++)
        C[(size_t)(r0 + mi * 16 + r) * N + (c0 + ni * 16)] = acc[mi][ni][r];
}

// -------- flash attention v10: in-block kv-split, Q pre-scaled (unchanged)
__global__ __launch_bounds__(512, 1) void flash_attn10(
    const bf16* __restrict__ Qh, const bf16* __restrict__ Kh,
    const bf16* __restrict__ Vt, bf16* __restrict__ Y) {
  __shared__ alignas(16) bf16 KB[4][64 * 128];   // [buf=set*2+grp][key][hd] 256B rows swz
  __shared__ alignas(16) bf16 VB[4][128 * 64];   // [buf][hd][key] 128B rows swz
  __shared__ float MLs[128][2];
  const int tid = threadIdx.x, lane = tid & 63, w = tid >> 6;
  const int hi = lane >> 5, lq = lane & 31;
  const int grp = w >> 2, wl = w & 3;

  const int g = blockIdx.x;
  const int bh = (g & 7) * 4 + ((g >> 3) & 3);   // XCD-grouped bh
  const int p  = g >> 5;                         // 0..7
  const int b = bh >> 4, h = bh & 15, kvh = h >> 1;

  const bf16* Qg = Qh + (size_t)(b * 16 + h) * 2048 * 128;
  const bf16* Kg = Kh + (size_t)(b * 8 + kvh) * 2048 * 128;
  const bf16* Vg = Vt + (size_t)(b * 8 + kvh) * 128 * 2048;

  short8 qf[8];
  f32x16 oacc[4];
  float m, l;
  int qw = 0, qg = 0;

  auto stage2 = [&](int set, int k0e) {
#pragma unroll
    for (int gb = 0; gb < 2; gb++) {
      const int k0 = k0e + gb * 64;
      char* kb = (char*)KB[set * 2 + gb];
      char* vb = (char*)VB[set * 2 + gb];
#pragma unroll
      for (int i = 0; i < 2; i++) {
        int c = w * 2 + i;
        {
          int row = c * 4 + (lane >> 4);
          int cb = ((lane & 15) * 16) ^ ((row & 7) << 4);
          async_ld16((const char*)Kg + (size_t)(k0 + row) * 256 + cb, kb + c * 1024);
        }
        {
          int row = c * 8 + (lane >> 3);
          int cb = ((lane & 7) * 16) ^ ((row & 7) << 4);
          async_ld16((const char*)Vg + (size_t)row * 4096 + (size_t)k0 * 2 + cb, vb + c * 1024);
        }
      }
    }
  };

  auto setupTile = [&](int q0) {
    qw = q0 + wl * 32;
    qg = qw + lq;
#pragma unroll
    for (int dc = 0; dc < 8; dc++)
      qf[dc] = *(const short8*)(Qg + (size_t)qg * 128 + dc * 16 + hi * 8);
#pragma unroll
    for (int dc = 0; dc < 4; dc++)
#pragma unroll
      for (int r = 0; r < 16; r++) oacc[dc][r] = 0.f;
    m = -1e30f;
    l = 0.f;
  };

  auto computeStep = [&](int bufI, int k0) {
    f32x16 st[2] = {};
#pragma unroll
    for (int kc = 0; kc < 2; kc++) {
      int row = kc * 32 + lq;
      int swz = (row & 7) << 4;
      const char* kbase = (const char*)KB[bufI] + row * 256;
#pragma unroll
      for (int dc = 0; dc < 8; dc++) {
        short8 kf = *(const short8*)(kbase + ((dc * 32 + hi * 16) ^ swz));
        st[kc] = __builtin_amdgcn_mfma_f32_32x32x16_bf16(kf, qf[dc], st[kc], 0, 0, 0);
      }
    }
    const bool msk = (k0 + 63 > qw);
    if (msk) {
#pragma unroll
      for (int kc = 0; kc < 2; kc++)
#pragma unroll
        for (int rr = 0; rr < 16; rr++) {
          int kg = k0 + kc * 32 + (rr & 3) + 8 * (rr >> 2) + 4 * hi;
          if (kg > qg) st[kc][rr] = -1e30f;
        }
    }
    float mx[16];
#pragma unroll
    for (int rr = 0; rr < 16; rr++) mx[rr] = fmaxf(st[0][rr], st[1][rr]);
#pragma unroll
    for (int off = 8; off >= 1; off >>= 1)
#pragma unroll
      for (int rr = 0; rr < 8; rr++)
        if (rr < off) mx[rr] = fmaxf(mx[rr], mx[rr + off]);
    float pm = fmaxf(mx[0], __shfl_xor(mx[0], 32));
    if (__any(pm > m + 8.f)) {
      float mnew = fmaxf(m, pm);
      float alpha = exp2f(m - mnew);
      m = mnew;
      l *= alpha;
      float al[16];
#pragma unroll
      for (int rr = 0; rr < 16; rr++)
        al[rr] = __shfl(alpha, (rr & 3) + 8 * (rr >> 2) + 4 * hi);
#pragma unroll
      for (int dc = 0; dc < 4; dc++)
#pragma unroll
        for (int rr = 0; rr < 16; rr++) oacc[dc][rr] *= al[rr];
    }
#pragma unroll
    for (int kc = 0; kc < 2; kc++)
#pragma unroll
      for (int rr = 0; rr < 16; rr++) st[kc][rr] = exp2f(st[kc][rr] - m);
    float sm[16];
#pragma unroll
    for (int rr = 0; rr < 16; rr++) sm[rr] = st[0][rr] + st[1][rr];
#pragma unroll
    for (int off = 8; off >= 1; off >>= 1)
#pragma unroll
      for (int rr = 0; rr < 8; rr++)
        if (rr < off) sm[rr] += sm[rr + off];
    l += sm[0] + __shfl_xor(sm[0], 32);
    short8 af[4];
#pragma unroll
    for (int kc = 0; kc < 2; kc++)
#pragma unroll
      for (int sb = 0; sb < 2; sb++) {
        int base = sb * 8;
        unsigned int a01 = cvt_pk_bf16(st[kc][base + 0], st[kc][base + 1]);
        unsigned int a23 = cvt_pk_bf16(st[kc][base + 2], st[kc][base + 3]);
        unsigned int b01 = cvt_pk_bf16(st[kc][base + 4], st[kc][base + 5]);
        unsigned int b23 = cvt_pk_bf16(st[kc][base + 6], st[kc][base + 7]);
        unsigned int xa01 = (unsigned int)__shfl_xor((int)a01, 32);
        unsigned int xa23 = (unsigned int)__shfl_xor((int)a23, 32);
        unsigned int xb01 = (unsigned int)__shfl_xor((int)b01, 32);
        unsigned int xb23 = (unsigned int)__shfl_xor((int)b23, 32);
        union { unsigned int u[4]; short8 s; } f;
        f.u[0] = hi ? xb01 : a01;
        f.u[1] = hi ? xb23 : a23;
        f.u[2] = hi ? b01 : xa01;
        f.u[3] = hi ? b23 : xa23;
        af[kc * 2 + sb] = f.s;
      }
#pragma unroll
    for (int dc = 0; dc < 4; dc++) {
      int row = dc * 32 + lq;
      int swz = (row & 7) << 4;
      const char* vbase = (const char*)VB[bufI] + row * 128;
#pragma unroll
      for (int ks = 0; ks < 4; ks++) {
        short8 vf = *(const short8*)(vbase + ((ks * 32 + hi * 16) ^ swz));
        oacc[dc] = __builtin_amdgcn_mfma_f32_32x32x16_bf16(af[ks], vf, oacc[dc], 0, 0, 0);
      }
    }
  };

  auto runRounds = [&](int n) {
    const int R = n >> 1;
    for (int r = 0; r < R; ++r) {
      asm volatile("s_waitcnt vmcnt(0)" ::: "memory");
      __builtin_amdgcn_s_barrier();
      if (r + 1 < R) stage2((r + 1) & 1, (2 * r + 2) * 64);
      __builtin_amdgcn_sched_barrier(0);
      const int s = 2 * r + grp, k0 = s * 64;
      const int bufI = (r & 1) * 2 + grp;
      if (k0 < qw + 32) computeStep(bufI, k0);
    }
  };

  auto writePartials = [&]() {
    float* base = (wl < 2) ? (float*)KB[2] : (float*)VB[2];
#pragma unroll
    for (int dc = 0; dc < 4; dc++)
#pragma unroll
      for (int rr = 0; rr < 16; rr++) {
        int q = (wl & 1) * 32 + (rr & 3) + 8 * (rr >> 2) + 4 * hi;
        base[q * 128 + dc * 32 + lq] = oacc[dc][rr];
      }
    if (lane < 32) {
      MLs[wl * 32 + lane][0] = m;
      MLs[wl * 32 + lane][1] = l;
    }
  };

  auto mergeAndY = [&](int q0) {
    float m1 = MLs[wl * 32 + lq][0], l1 = MLs[wl * 32 + lq][1];
    float mN = fmaxf(m, m1);
    float e0 = exp2f(m - mN), e1 = exp2f(m1 - mN);
    float lT = l * e0 + l1 * e1;
    float inv = 1.f / lT;
    float e0r[16], e1r[16], ivr[16];
#pragma unroll
    for (int rr = 0; rr < 16; rr++) {
      int src = (rr & 3) + 8 * (rr >> 2) + 4 * hi;
      e0r[rr] = __shfl(e0, src);
      e1r[rr] = __shfl(e1, src);
      ivr[rr] = __shfl(inv, src);
    }
    const float* base = (wl < 2) ? (const float*)KB[2] : (const float*)VB[2];
#pragma unroll
    for (int dc = 0; dc < 4; dc++)
#pragma unroll
      for (int rr = 0; rr < 16; rr++) {
        int q = (wl & 1) * 32 + (rr & 3) + 8 * (rr >> 2) + 4 * hi;
        float o1 = base[q * 128 + dc * 32 + lq];
        float oT = oacc[dc][rr] * e0r[rr] + o1 * e1r[rr];
        int t = q0 + wl * 32 + (rr & 3) + 8 * (rr >> 2) + 4 * hi;
        Y[(size_t)(b * 2048 + t) * 2048 + h * 128 + dc * 32 + lq] =
            __float2bfloat16(oT * ivr[rr]);
      }
  };

  const int jA = 15 - p, jB = p;
  const int q0A = jA * 128, nA = 2 * jA + 2;
  const int q0B = jB * 128, nB = 2 * jB + 2;

  setupTile(q0A);
  stage2(0, 0);
  runRounds(nA);
  __syncthreads();
  stage2(0, 0);
  if (grp == 1) writePartials();
  __syncthreads();
  if (grp == 0) mergeAndY(q0A);
  setupTile(q0B);
  runRounds(nB);
  __syncthreads();
  if (grp == 1) writePartials();
  __syncthreads();
  if (grp == 0) mergeAndY(q0B);
}

// ---------------------------------------------------------------- launcher
extern "C" void kernel_launch(void* const* d_in, const int* in_sizes, int n_in,
                              void* d_out, int out_size, void* d_ws, size_t ws_size,
                              hipStream_t stream) {
  (void)in_sizes; (void)n_in; (void)out_size; (void)ws_size;
  const float* x   = (const float*)d_in[0];
  const float* wq  = (const float*)d_in[1];
  const float* wk  = (const float*)d_in[2];
  const float* wv  = (const float*)d_in[3];
  const float* wo  = (const float*)d_in[4];
  const float* qnw = (const float*)d_in[5];
  const float* knw = (const float*)d_in[6];
  float* out = (float*)d_out;
  char* ws = (char*)d_ws;
  const size_t MB = 1u << 20;
  bf16*   xb  = (bf16*)(ws + 0 * MB);    // [4096][1024]
  bf16*   wt  = (bf16*)(ws + 8 * MB);    // [4096][1024]  rows: wq^T | wk^T | wv^T
  bf16*   wot = (bf16*)(ws + 16 * MB);   // [1024][2048]
  float2* tab = (float2*)(ws + 52 * MB); // [2048][64]
  bf16*   Qh  = (bf16*)(ws + 53 * MB);   // [2][16][2048][128] (pre-scaled)
  bf16*   Kh  = (bf16*)(ws + 69 * MB);   // [2][8][2048][128]
  bf16*   Vtr = (bf16*)(ws + 77 * MB);   // [2][8][128][2048]  (V transposed)
  bf16*   Yb  = (bf16*)(ws + 85 * MB);   // [4096][2048]

  cvt_f32_bf16<<<4096, 256, 0, stream>>>(x, xb, 1048576);
  transpose_cvt3<<<dim3(32, 32, 4), 256, 0, stream>>>(wq, wk, wv, wt);
  transpose_cvt<<<dim3(32, 64), 256, 0, stream>>>(wo, wot, 2048, 1024);
  rope_tab<<<2048, 64, 0, stream>>>(tab);
  gemm_qkv<<<dim3(32, 32), 256, 0, stream>>>(xb, wt, qnw, knw, tab, Qh, Kh, Vtr);
  flash_attn10<<<256, 512, 0, stream>>>(Qh, Kh, Vtr, Yb);
  gemm_out<<<dim3(8, 32), 256, 0, stream>>>(Yb, wot, out, 4096, 1024, 2048);
}

// Round 14
// 156.176 us; speedup vs baseline: 1.1324x; 1.0667x over previous
//
#include <hip/hip_runtime.h>
#include <hip/hip_bf16.h>
#include <cstdint>
#include <cstddef>

using bf16 = __hip_bfloat16;
using short8 = __attribute__((ext_vector_type(8))) short;
using f32x4  = __attribute__((ext_vector_type(4))) float;
using f32x16 = __attribute__((ext_vector_type(16))) float;

#define DEVI __device__ __forceinline__

// async global->LDS, 16B per lane. LDS dest is wave-uniform base + lane*16.
DEVI void async_ld16(const void* g, void* l) {
  __builtin_amdgcn_global_load_lds(
      (const __attribute__((address_space(1))) unsigned int*)g,
      (__attribute__((address_space(3))) unsigned int*)l, 16, 0, 0);
}

DEVI unsigned int cvt_pk_bf16(float lo, float hi) {
  unsigned int r;
  asm("v_cvt_pk_bf16_f32 %0, %1, %2" : "=v"(r) : "v"(lo), "v"(hi));
  return r;
}

// ---------- fused prep: x->bf16 cvt | wq/wk/wv transpose | wo transpose | rope table
// flat z-dispatch: [0,4096) cvt, [4096,8192) qkv-w transpose, [8192,10240) wo, [10240,10752) rope
__global__ __launch_bounds__(256) void prep(
    const float* __restrict__ x, const float* __restrict__ wq,
    const float* __restrict__ wk, const float* __restrict__ wv,
    const float* __restrict__ wo, bf16* __restrict__ xb,
    bf16* __restrict__ wt, bf16* __restrict__ wot, float2* __restrict__ tab) {
  const int z = blockIdx.x, tid = threadIdx.x;
  if (z < 4096) {
    // ---- cvt f32->bf16, 4 floats/thread
    int i = z * 256 + tid;
    float4 v = ((const float4*)x)[i];
    union { bf16 h[4]; ushort4 u; } o;
    o.h[0] = __float2bfloat16(v.x);
    o.h[1] = __float2bfloat16(v.y);
    o.h[2] = __float2bfloat16(v.z);
    o.h[3] = __float2bfloat16(v.w);
    ((ushort4*)xb)[i] = o.u;
  } else if (z < 10240) {
    // ---- 32x32 transpose tiles
    __shared__ float tile[32][33];
    const float* src; bf16* dst; int N, K, n0, k0, roff;
    if (z < 8192) {
      int z2 = z - 4096;
      int xb_ = z2 & 31, yb = (z2 >> 5) & 31, zz = z2 >> 10;
      if (zz < 2)       { src = wq; N = 2048; n0 = zz * 1024 + xb_ * 32; roff = zz * 1024 + xb_ * 32; }
      else if (zz == 2) { src = wk; N = 1024; n0 = xb_ * 32; roff = 2048 + xb_ * 32; }
      else              { src = wv; N = 1024; n0 = xb_ * 32; roff = 3072 + xb_ * 32; }
      K = 1024; k0 = yb * 32; dst = wt;
    } else {
      int z3 = z - 8192;
      int xb_ = z3 & 31, yb = z3 >> 5;
      src = wo; N = 1024; K = 2048; n0 = xb_ * 32; k0 = yb * 32; roff = xb_ * 32;
      dst = wot;
    }
    int tx = tid & 31, ty = tid >> 5;
#pragma unroll
    for (int i = 0; i < 32; i += 8)
      tile[ty + i][tx] = src[(size_t)(k0 + ty + i) * N + n0 + tx];
    __syncthreads();
#pragma unroll
    for (int i = 0; i < 32; i += 8)
      dst[(size_t)(roff + ty + i) * K + k0 + tx] = __float2bfloat16(tile[tx][ty + i]);
  } else {
    // ---- rope table: 4 t-values per block
    int z4 = z - 10240;
    int t = z4 * 4 + (tid >> 6), i = tid & 63;
    float ex = -2.f * (float)i * (1.f / 128.f);
    float theta = exp2f(ex * 19.9315685693241741f);  // log2(1e6)
    float f = (float)t * theta;
    float sv, cv;
    sincosf(f, &sv, &cv);
    tab[t * 64 + i] = make_float2(cv, sv);
  }
}

// ------- fused QKV GEMM (128x128, 2-deep counted vmcnt(8), 2 blocks/CU) with
// per-head epilogue: bx<16 Q-head (RMSNorm+RoPE+scale -> Qh), 16..23 K-head
// (RMSNorm+RoPE -> Kh), 24..31 V-head (LDS transpose -> Vt[d][t]).
__global__ __launch_bounds__(256, 2) void gemm_qkv(
    const bf16* __restrict__ A, const bf16* __restrict__ Bt,
    const float* __restrict__ qnw, const float* __restrict__ knw,
    const float2* __restrict__ tab,
    bf16* __restrict__ Qh, bf16* __restrict__ Kh, bf16* __restrict__ Vt) {
  __shared__ alignas(16) bf16 As[2][128 * 64];
  __shared__ alignas(16) bf16 Bs[2][128 * 64];
  const int tid = threadIdx.x, lane = tid & 63, w = tid >> 6;
  const int wm = w >> 1, wn = w & 1;
  const int bx = blockIdx.x;
  const int m0 = blockIdx.y * 128, n0 = bx * 128;
  const int K = 1024, nt = 16;
  f32x4 acc[4][4] = {};

  const int srow = lane >> 3;
  const int scb  = (lane & 7) * 16;

  auto stage = [&](int buf, int kt) {
#pragma unroll
    for (int i = 0; i < 4; i++) {
      int row = w * 32 + i * 8 + srow;
      int src_cb = scb ^ ((row & 7) << 4);
      async_ld16((const char*)(A  + (size_t)(m0 + row) * K + kt * 64) + src_cb,
                 (char*)As[buf] + w * 4096 + i * 1024);
      async_ld16((const char*)(Bt + (size_t)(n0 + row) * K + kt * 64) + src_cb,
                 (char*)Bs[buf] + w * 4096 + i * 1024);
    }
  };

  stage(0, 0);
  stage(1, 1);

  for (int kt = 0; kt < nt; ++kt) {
    const int buf = kt & 1;
    if (kt + 1 < nt) asm volatile("s_waitcnt vmcnt(8)" ::: "memory");
    else             asm volatile("s_waitcnt vmcnt(0)" ::: "memory");
    __builtin_amdgcn_s_barrier();
#pragma unroll
    for (int ks = 0; ks < 2; ks++) {
      short8 af[4], bfr[4];
#pragma unroll
      for (int mi = 0; mi < 4; mi++) {
        int row = wm * 64 + mi * 16 + (lane & 15);
        int cb = (ks * 64 + (lane >> 4) * 16) ^ ((row & 7) << 4);
        af[mi] = *(const short8*)((const char*)As[buf] + row * 128 + cb);
      }
#pragma unroll
      for (int ni = 0; ni < 4; ni++) {
        int row = wn * 64 + ni * 16 + (lane & 15);
        int cb = (ks * 64 + (lane >> 4) * 16) ^ ((row & 7) << 4);
        bfr[ni] = *(const short8*)((const char*)Bs[buf] + row * 128 + cb);
      }
#pragma unroll
      for (int mi = 0; mi < 4; mi++)
#pragma unroll
        for (int ni = 0; ni < 4; ni++)
          acc[mi][ni] = __builtin_amdgcn_mfma_f32_16x16x32_bf16(af[mi], bfr[ni], acc[mi][ni], 0, 0, 0);
    }
    __builtin_amdgcn_s_barrier();
    __builtin_amdgcn_sched_barrier(0);
    if (kt + 2 < nt) stage(buf, kt + 2);
  }

  const int b = m0 >> 11;  // uniform per block (128 | 2048)

  if (bx < 24) {
    // ---------- Q/K epilogue: RMSNorm + RoPE, write head-major layout
    __syncthreads();                     // all LDS traffic of main loop done
    float* ssb = (float*)As;             // [2 (wn)][128 rows] partial sum-sq
    float s[4][4];
#pragma unroll
    for (int mi = 0; mi < 4; mi++)
#pragma unroll
      for (int r = 0; r < 4; r++) {
        float v0 = acc[mi][0][r], v1 = acc[mi][1][r];
        float v2 = acc[mi][2][r], v3 = acc[mi][3][r];
        float t = v0 * v0 + v1 * v1 + v2 * v2 + v3 * v3;
        t += __shfl_xor(t, 1);
        t += __shfl_xor(t, 2);
        t += __shfl_xor(t, 4);
        t += __shfl_xor(t, 8);
        s[mi][r] = t;
      }
    if ((lane & 15) == 0) {
#pragma unroll
      for (int mi = 0; mi < 4; mi++)
#pragma unroll
        for (int r = 0; r < 4; r++)
          ssb[wn * 128 + wm * 64 + mi * 16 + (lane >> 4) * 4 + r] = s[mi][r];
    }
    __syncthreads();

    const int isQ = (bx < 16);
    const int h = isQ ? bx : bx - 16;
    const float* wnp = isQ ? qnw : knw;
    bf16* dst = isQ ? Qh : Kh;
    const int NHH = isQ ? 16 : 8;
    const float qs = isQ ? 0.12751744416163417f : 1.f;  // fold softmax*log2e into Q
    float wd[4];
#pragma unroll
    for (int ni = 0; ni < 4; ni++) wd[ni] = wnp[wn * 64 + ni * 16 + (lane & 15)];

#pragma unroll
    for (int mi = 0; mi < 4; mi++)
#pragma unroll
      for (int r = 0; r < 4; r++) {
        int rl = wm * 64 + mi * 16 + (lane >> 4) * 4 + r;
        float tot = ssb[rl] + ssb[128 + rl];
        float inv = qs / (sqrtf(tot * 0.0078125f) + 1e-6f);
        int t = (m0 + rl) & 2047;
        bf16* drow = dst + ((size_t)(b * NHH + h) * 2048 + t) * 128;
#pragma unroll
        for (int ni = 0; ni < 4; ni++) {
          int d = wn * 64 + ni * 16 + (lane & 15);
          float val = acc[mi][ni][r] * inv * wd[ni];
          float prt = __shfl_xor(val, 1);
          float2 cs = tab[t * 64 + (d >> 1)];
          float o = (d & 1) ? (prt * cs.y + val * cs.x)
                            : (val * cs.x - prt * cs.y);
          drow[d] = __float2bfloat16(o);
        }
      }
  } else {
    // ---------- V epilogue: transpose 128x128 tile via LDS -> Vt[b*8+vh][d][t]
    __syncthreads();
    bf16* vt = (bf16*)As;                // [128 d][128 t] rows 256B, XOR-swizzled
    const int vh = bx - 24;
#pragma unroll
    for (int mi = 0; mi < 4; mi++)
#pragma unroll
      for (int ni = 0; ni < 4; ni++) {
        int d = wn * 64 + ni * 16 + (lane & 15);
        int tl = wm * 64 + mi * 16 + (lane >> 4) * 4;
        unsigned int p0 = cvt_pk_bf16(acc[mi][ni][0], acc[mi][ni][1]);
        unsigned int p1 = cvt_pk_bf16(acc[mi][ni][2], acc[mi][ni][3]);
        int byte = d * 256 + ((tl * 2) ^ ((d & 7) << 4));
        *(uint2*)((char*)vt + byte) = make_uint2(p0, p1);
      }
    __syncthreads();
    bf16* dstV = Vt + (size_t)(b * 8 + vh) * 128 * 2048 + (m0 & 2047);
#pragma unroll
    for (int i = 0; i < 8; i++) {
      int flat = tid + i * 256;          // 2048 granules: d = flat>>4, g = flat&15
      int d = flat >> 4, g = flat & 15;
      short8 v = *(const short8*)((const char*)vt + d * 256 + ((g * 16) ^ ((d & 7) << 4)));
      *(short8*)(dstV + (size_t)d * 2048 + g * 8) = v;
    }
  }
}

// ------- out-proj GEMM, 64x128 tile, 2-deep counted vmcnt(6), 3 blocks/CU, f32 out
__global__ __launch_bounds__(256, 3) void gemm_out64(
    const bf16* __restrict__ A, const bf16* __restrict__ Bt,
    float* __restrict__ C, int M, int N, int K) {
  __shared__ alignas(16) bf16 As[2][64 * 64];    // 8KB per buf
  __shared__ alignas(16) bf16 Bs[2][128 * 64];   // 16KB per buf
  const int tid = threadIdx.x, lane = tid & 63, w = tid >> 6;
  const int m0 = blockIdx.y * 64, n0 = blockIdx.x * 128;
  const int nt = K >> 6;
  f32x4 acc[4][2] = {};   // [mi][ni]: rows mi*16, cols w*32+ni*16

  auto stage = [&](int buf, int kt) {
#pragma unroll
    for (int i = 0; i < 2; i++) {        // A: 512 granules
      int c = tid + i * 256;
      int row = c >> 3;
      int cb = ((c & 7) * 16) ^ ((row & 7) << 4);
      async_ld16((const char*)(A + (size_t)(m0 + row) * K + kt * 64) + cb,
                 (char*)As[buf] + i * 4096 + tid * 16);
    }
#pragma unroll
    for (int i = 0; i < 4; i++) {        // B: 1024 granules
      int c = tid + i * 256;
      int row = c >> 3;
      int cb = ((c & 7) * 16) ^ ((row & 7) << 4);
      async_ld16((const char*)(Bt + (size_t)(n0 + row) * K + kt * 64) + cb,
                 (char*)Bs[buf] + i * 4096 + tid * 16);
    }
  };

  stage(0, 0);
  stage(1, 1);

  for (int kt = 0; kt < nt; ++kt) {
    const int buf = kt & 1;
    if (kt + 1 < nt) asm volatile("s_waitcnt vmcnt(6)" ::: "memory");
    else             asm volatile("s_waitcnt vmcnt(0)" ::: "memory");
    __builtin_amdgcn_s_barrier();
#pragma unroll
    for (int ks = 0; ks < 2; ks++) {
      short8 af[4], bfr[2];
#pragma unroll
      for (int mi = 0; mi < 4; mi++) {
        int row = mi * 16 + (lane & 15);
        int cb = (ks * 64 + (lane >> 4) * 16) ^ ((row & 7) << 4);
        af[mi] = *(const short8*)((const char*)As[buf] + row * 128 + cb);
      }
#pragma unroll
      for (int ni = 0; ni < 2; ni++) {
        int row = w * 32 + ni * 16 + (lane & 15);
        int cb = (ks * 64 + (lane >> 4) * 16) ^ ((row & 7) << 4);
        bfr[ni] = *(const short8*)((const char*)Bs[buf] + row * 128 + cb);
      }
#pragma unroll
      for (int mi = 0; mi < 4; mi++)
#pragma unroll
        for (int ni = 0; ni < 2; ni++)
          acc[mi][ni] = __builtin_amdgcn_mfma_f32_16x16x32_bf16(af[mi], bfr[ni], acc[mi][ni], 0, 0, 0);
    }
    __builtin_amdgcn_s_barrier();
    __builtin_amdgcn_sched_barrier(0);
    if (kt + 2 < nt) stage(buf, kt + 2);
  }

  const int c0 = n0 + w * 32 + (lane & 15);
  const int r0 = m0 + (lane >> 4) * 4;
#pragma unroll
  for (int mi = 0; mi < 4; mi++)
#pragma unroll
    for (int ni = 0; ni < 2; ni++)
#pragma unroll
      for (int r = 0; r < 4; r++)
        C[(size_t)(r0 + mi * 16 + r) * N + (c0 + ni * 16)] = acc[mi][ni][r];
}

// -------- flash attention v10: in-block kv-split, Q pre-scaled (unchanged)
__global__ __launch_bounds__(512, 1) void flash_attn10(
    const bf16* __restrict__ Qh, const bf16* __restrict__ Kh,
    const bf16* __restrict__ Vt, bf16* __restrict__ Y) {
  __shared__ alignas(16) bf16 KB[4][64 * 128];   // [buf=set*2+grp][key][hd] 256B rows swz
  __shared__ alignas(16) bf16 VB[4][128 * 64];   // [buf][hd][key] 128B rows swz
  __shared__ float MLs[128][2];
  const int tid = threadIdx.x, lane = tid & 63, w = tid >> 6;
  const int hi = lane >> 5, lq = lane & 31;
  const int grp = w >> 2, wl = w & 3;

  const int g = blockIdx.x;
  const int bh = (g & 7) * 4 + ((g >> 3) & 3);   // XCD-grouped bh
  const int p  = g >> 5;                         // 0..7
  const int b = bh >> 4, h = bh & 15, kvh = h >> 1;

  const bf16* Qg = Qh + (size_t)(b * 16 + h) * 2048 * 128;
  const bf16* Kg = Kh + (size_t)(b * 8 + kvh) * 2048 * 128;
  const bf16* Vg = Vt + (size_t)(b * 8 + kvh) * 128 * 2048;

  short8 qf[8];
  f32x16 oacc[4];
  float m, l;
  int qw = 0, qg = 0;

  auto stage2 = [&](int set, int k0e) {
#pragma unroll
    for (int gb = 0; gb < 2; gb++) {
      const int k0 = k0e + gb * 64;
      char* kb = (char*)KB[set * 2 + gb];
      char* vb = (char*)VB[set * 2 + gb];
#pragma unroll
      for (int i = 0; i < 2; i++) {
        int c = w * 2 + i;
        {
          int row = c * 4 + (lane >> 4);
          int cb = ((lane & 15) * 16) ^ ((row & 7) << 4);
          async_ld16((const char*)Kg + (size_t)(k0 + row) * 256 + cb, kb + c * 1024);
        }
        {
          int row = c * 8 + (lane >> 3);
          int cb = ((lane & 7) * 16) ^ ((row & 7) << 4);
          async_ld16((const char*)Vg + (size_t)row * 4096 + (size_t)k0 * 2 + cb, vb + c * 1024);
        }
      }
    }
  };

  auto setupTile = [&](int q0) {
    qw = q0 + wl * 32;
    qg = qw + lq;
#pragma unroll
    for (int dc = 0; dc < 8; dc++)
      qf[dc] = *(const short8*)(Qg + (size_t)qg * 128 + dc * 16 + hi * 8);
#pragma unroll
    for (int dc = 0; dc < 4; dc++)
#pragma unroll
      for (int r = 0; r < 16; r++) oacc[dc][r] = 0.f;
    m = -1e30f;
    l = 0.f;
  };

  auto computeStep = [&](int bufI, int k0) {
    f32x16 st[2] = {};
#pragma unroll
    for (int kc = 0; kc < 2; kc++) {
      int row = kc * 32 + lq;
      int swz = (row & 7) << 4;
      const char* kbase = (const char*)KB[bufI] + row * 256;
#pragma unroll
      for (int dc = 0; dc < 8; dc++) {
        short8 kf = *(const short8*)(kbase + ((dc * 32 + hi * 16) ^ swz));
        st[kc] = __builtin_amdgcn_mfma_f32_32x32x16_bf16(kf, qf[dc], st[kc], 0, 0, 0);
      }
    }
    const bool msk = (k0 + 63 > qw);
    if (msk) {
#pragma unroll
      for (int kc = 0; kc < 2; kc++)
#pragma unroll
        for (int rr = 0; rr < 16; rr++) {
          int kg = k0 + kc * 32 + (rr & 3) + 8 * (rr >> 2) + 4 * hi;
          if (kg > qg) st[kc][rr] = -1e30f;
        }
    }
    float mx[16];
#pragma unroll
    for (int rr = 0; rr < 16; rr++) mx[rr] = fmaxf(st[0][rr], st[1][rr]);
#pragma unroll
    for (int off = 8; off >= 1; off >>= 1)
#pragma unroll
      for (int rr = 0; rr < 8; rr++)
        if (rr < off) mx[rr] = fmaxf(mx[rr], mx[rr + off]);
    float pm = fmaxf(mx[0], __shfl_xor(mx[0], 32));
    if (__any(pm > m + 8.f)) {
      float mnew = fmaxf(m, pm);
      float alpha = exp2f(m - mnew);
      m = mnew;
      l *= alpha;
      float al[16];
#pragma unroll
      for (int rr = 0; rr < 16; rr++)
        al[rr] = __shfl(alpha, (rr & 3) + 8 * (rr >> 2) + 4 * hi);
#pragma unroll
      for (int dc = 0; dc < 4; dc++)
#pragma unroll
        for (int rr = 0; rr < 16; rr++) oacc[dc][rr] *= al[rr];
    }
#pragma unroll
    for (int kc = 0; kc < 2; kc++)
#pragma unroll
      for (int rr = 0; rr < 16; rr++) st[kc][rr] = exp2f(st[kc][rr] - m);
    float sm[16];
#pragma unroll
    for (int rr = 0; rr < 16; rr++) sm[rr] = st[0][rr] + st[1][rr];
#pragma unroll
    for (int off = 8; off >= 1; off >>= 1)
#pragma unroll
      for (int rr = 0; rr < 8; rr++)
        if (rr < off) sm[rr] += sm[rr + off];
    l += sm[0] + __shfl_xor(sm[0], 32);
    short8 af[4];
#pragma unroll
    for (int kc = 0; kc < 2; kc++)
#pragma unroll
      for (int sb = 0; sb < 2; sb++) {
        int base = sb * 8;
        unsigned int a01 = cvt_pk_bf16(st[kc][base + 0], st[kc][base + 1]);
        unsigned int a23 = cvt_pk_bf16(st[kc][base + 2], st[kc][base + 3]);
        unsigned int b01 = cvt_pk_bf16(st[kc][base + 4], st[kc][base + 5]);
        unsigned int b23 = cvt_pk_bf16(st[kc][base + 6], st[kc][base + 7]);
        unsigned int xa01 = (unsigned int)__shfl_xor((int)a01, 32);
        unsigned int xa23 = (unsigned int)__shfl_xor((int)a23, 32);
        unsigned int xb01 = (unsigned int)__shfl_xor((int)b01, 32);
        unsigned int xb23 = (unsigned int)__shfl_xor((int)b23, 32);
        union { unsigned int u[4]; short8 s; } f;
        f.u[0] = hi ? xb01 : a01;
        f.u[1] = hi ? xb23 : a23;
        f.u[2] = hi ? b01 : xa01;
        f.u[3] = hi ? b23 : xa23;
        af[kc * 2 + sb] = f.s;
      }
#pragma unroll
    for (int dc = 0; dc < 4; dc++) {
      int row = dc * 32 + lq;
      int swz = (row & 7) << 4;
      const char* vbase = (const char*)VB[bufI] + row * 128;
#pragma unroll
      for (int ks = 0; ks < 4; ks++) {
        short8 vf = *(const short8*)(vbase + ((ks * 32 + hi * 16) ^ swz));
        oacc[dc] = __builtin_amdgcn_mfma_f32_32x32x16_bf16(af[ks], vf, oacc[dc], 0, 0, 0);
      }
    }
  };

  auto runRounds = [&](int n) {
    const int R = n >> 1;
    for (int r = 0; r < R; ++r) {
      asm volatile("s_waitcnt vmcnt(0)" ::: "memory");
      __builtin_amdgcn_s_barrier();
      if (r + 1 < R) stage2((r + 1) & 1, (2 * r + 2) * 64);
      __builtin_amdgcn_sched_barrier(0);
      const int s = 2 * r + grp, k0 = s * 64;
      const int bufI = (r & 1) * 2 + grp;
      if (k0 < qw + 32) computeStep(bufI, k0);
    }
  };

  auto writePartials = [&]() {
    float* base = (wl < 2) ? (float*)KB[2] : (float*)VB[2];
#pragma unroll
    for (int dc = 0; dc < 4; dc++)
#pragma unroll
      for (int rr = 0; rr < 16; rr++) {
        int q = (wl & 1) * 32 + (rr & 3) + 8 * (rr >> 2) + 4 * hi;
        base[q * 128 + dc * 32 + lq] = oacc[dc][rr];
      }
    if (lane < 32) {
      MLs[wl * 32 + lane][0] = m;
      MLs[wl * 32 + lane][1] = l;
    }
  };

  auto mergeAndY = [&](int q0) {
    float m1 = MLs[wl * 32 + lq][0], l1 = MLs[wl * 32 + lq][1];
    float mN = fmaxf(m, m1);
    float e0 = exp2f(m - mN), e1 = exp2f(m1 - mN);
    float lT = l * e0 + l1 * e1;
    float inv = 1.f / lT;
    float e0r[16], e1r[16], ivr[16];
#pragma unroll
    for (int rr = 0; rr < 16; rr++) {
      int src = (rr & 3) + 8 * (rr >> 2) + 4 * hi;
      e0r[rr] = __shfl(e0, src);
      e1r[rr] = __shfl(e1, src);
      ivr[rr] = __shfl(inv, src);
    }
    const float* base = (wl < 2) ? (const float*)KB[2] : (const float*)VB[2];
#pragma unroll
    for (int dc = 0; dc < 4; dc++)
#pragma unroll
      for (int rr = 0; rr < 16; rr++) {
        int q = (wl & 1) * 32 + (rr & 3) + 8 * (rr >> 2) + 4 * hi;
        float o1 = base[q * 128 + dc * 32 + lq];
        float oT = oacc[dc][rr] * e0r[rr] + o1 * e1r[rr];
        int t = q0 + wl * 32 + (rr & 3) + 8 * (rr >> 2) + 4 * hi;
        Y[(size_t)(b * 2048 + t) * 2048 + h * 128 + dc * 32 + lq] =
            __float2bfloat16(oT * ivr[rr]);
      }
  };

  const int jA = 15 - p, jB = p;
  const int q0A = jA * 128, nA = 2 * jA + 2;
  const int q0B = jB * 128, nB = 2 * jB + 2;

  setupTile(q0A);
  stage2(0, 0);
  runRounds(nA);
  __syncthreads();
  stage2(0, 0);
  if (grp == 1) writePartials();
  __syncthreads();
  if (grp == 0) mergeAndY(q0A);
  setupTile(q0B);
  runRounds(nB);
  __syncthreads();
  if (grp == 1) writePartials();
  __syncthreads();
  if (grp == 0) mergeAndY(q0B);
}

// ---------------------------------------------------------------- launcher
extern "C" void kernel_launch(void* const* d_in, const int* in_sizes, int n_in,
                              void* d_out, int out_size, void* d_ws, size_t ws_size,
                              hipStream_t stream) {
  (void)in_sizes; (void)n_in; (void)out_size; (void)ws_size;
  const float* x   = (const float*)d_in[0];
  const float* wq  = (const float*)d_in[1];
  const float* wk  = (const float*)d_in[2];
  const float* wv  = (const float*)d_in[3];
  const float* wo  = (const float*)d_in[4];
  const float* qnw = (const float*)d_in[5];
  const float* knw = (const float*)d_in[6];
  float* out = (float*)d_out;
  char* ws = (char*)d_ws;
  const size_t MB = 1u << 20;
  bf16*   xb  = (bf16*)(ws + 0 * MB);    // [4096][1024]
  bf16*   wt  = (bf16*)(ws + 8 * MB);    // [4096][1024]  rows: wq^T | wk^T | wv^T
  bf16*   wot = (bf16*)(ws + 16 * MB);   // [1024][2048]
  float2* tab = (float2*)(ws + 52 * MB); // [2048][64]
  bf16*   Qh  = (bf16*)(ws + 53 * MB);   // [2][16][2048][128] (pre-scaled)
  bf16*   Kh  = (bf16*)(ws + 69 * MB);   // [2][8][2048][128]
  bf16*   Vtr = (bf16*)(ws + 77 * MB);   // [2][8][128][2048]  (V transposed)
  bf16*   Yb  = (bf16*)(ws + 85 * MB);   // [4096][2048]

  prep<<<10752, 256, 0, stream>>>(x, wq, wk, wv, wo, xb, wt, wot, tab);
  gemm_qkv<<<dim3(32, 32), 256, 0, stream>>>(xb, wt, qnw, knw, tab, Qh, Kh, Vtr);
  flash_attn10<<<256, 512, 0, stream>>>(Qh, Kh, Vtr, Yb);
  gemm_out64<<<dim3(8, 64), 256, 0, stream>>>(Yb, wot, out, 4096, 1024, 2048);
}